// Round 1
// baseline (280.751 us; speedup 1.0000x reference)
//
#include <hip/hip_runtime.h>
#include <hip/hip_bf16.h>

// LocalSelfAttention: B=4, S=4096, E=1024, WINDOW=256, SCALE=0.125
// Pipeline: cast -> QKV gemm (bf16 MFMA) -> V transpose -> windowed attn -> O gemm (+bias+residual)

typedef unsigned short u16;
typedef __attribute__((ext_vector_type(8))) short short8;   // 8 bf16 (4 VGPRs)
typedef __attribute__((ext_vector_type(4))) float f32x4;

__device__ __forceinline__ u16 f2bf(float f) {
    __hip_bfloat16 h = __float2bfloat16(f);
    return __builtin_bit_cast(u16, h);
}

// ---------------- cast fp32 -> bf16, vectorized ----------------
__global__ void cast_f32_bf16(const float* __restrict__ src, u16* __restrict__ dst, int n) {
    int i = (blockIdx.x * 256 + threadIdx.x) * 8;
    if (i >= n) return;
    const float4* s = (const float4*)(src + i);
    float4 a = s[0], b = s[1];
    short8 o;
    o[0] = (short)f2bf(a.x); o[1] = (short)f2bf(a.y); o[2] = (short)f2bf(a.z); o[3] = (short)f2bf(a.w);
    o[4] = (short)f2bf(b.x); o[5] = (short)f2bf(b.y); o[6] = (short)f2bf(b.z); o[7] = (short)f2bf(b.w);
    *(short8*)(dst + i) = o;
}

// ---------------- GEMM: C[M,N] = A[M,K] @ B[N,K]^T + bias ----------------
// A, B bf16 K-major. EPI=0: bf16 out, bias selected from 3 arrays by col/1024 (QKV).
// EPI=1: fp32 out = acc + bias0 + resid (O-projection + residual).
template <int EPI>
__global__ __launch_bounds__(256, 2) void gemm_bt(
    const u16* __restrict__ A, const u16* __restrict__ B,
    int M, int N, int K,
    const float* __restrict__ bias0, const float* __restrict__ bias1, const float* __restrict__ bias2,
    u16* __restrict__ Cb, float* __restrict__ Cf, const float* __restrict__ resid)
{
    __shared__ __align__(16) u16 At[128 * 64];
    __shared__ __align__(16) u16 Bt[128 * 64];
    const int t = threadIdx.x;
    const int lane = t & 63;
    const int wid = t >> 6;
    const int wm = wid >> 1, wn = wid & 1;
    const int l15 = lane & 15, lk = lane >> 4;
    const int m0 = blockIdx.y * 128, n0 = blockIdx.x * 128;

    f32x4 acc[4][4];
#pragma unroll
    for (int m = 0; m < 4; ++m)
#pragma unroll
        for (int n = 0; n < 4; ++n)
            acc[m][n] = (f32x4){0.f, 0.f, 0.f, 0.f};

    for (int k0 = 0; k0 < K; k0 += 64) {
        __syncthreads();
#pragma unroll
        for (int p = 0; p < 4; ++p) {
            int e = p * 2048 + t * 8;
            int row = e >> 6, col = e & 63;
            short8 va = *(const short8*)(A + (size_t)(m0 + row) * K + k0 + col);
            *(short8*)((char*)At + row * 128 + ((col * 2) ^ ((row & 7) << 4))) = va;
            short8 vb = *(const short8*)(B + (size_t)(n0 + row) * K + k0 + col);
            *(short8*)((char*)Bt + row * 128 + ((col * 2) ^ ((row & 7) << 4))) = vb;
        }
        __syncthreads();
#pragma unroll
        for (int ks = 0; ks < 2; ++ks) {
            const int bc = ks * 64 + lk * 16;
            short8 af[4], bfr[4];
#pragma unroll
            for (int m = 0; m < 4; ++m) {
                int row = wm * 64 + m * 16 + l15;
                af[m] = *(const short8*)((char*)At + row * 128 + (bc ^ ((row & 7) << 4)));
            }
#pragma unroll
            for (int n = 0; n < 4; ++n) {
                int row = wn * 64 + n * 16 + l15;
                bfr[n] = *(const short8*)((char*)Bt + row * 128 + (bc ^ ((row & 7) << 4)));
            }
#pragma unroll
            for (int m = 0; m < 4; ++m)
#pragma unroll
                for (int n = 0; n < 4; ++n)
                    acc[m][n] = __builtin_amdgcn_mfma_f32_16x16x32_bf16(af[m], bfr[n], acc[m][n], 0, 0, 0);
        }
    }

#pragma unroll
    for (int m = 0; m < 4; ++m) {
#pragma unroll
        for (int n = 0; n < 4; ++n) {
            int col = n0 + wn * 64 + n * 16 + l15;
            float bv;
            if (EPI == 0)
                bv = (col < 1024) ? bias0[col] : (col < 2048) ? bias1[col - 1024] : bias2[col - 2048];
            else
                bv = bias0[col];
#pragma unroll
            for (int r = 0; r < 4; ++r) {
                int row = m0 + wm * 64 + m * 16 + lk * 4 + r;
                float v = acc[m][n][r] + bv;
                if (EPI == 0)
                    Cb[(size_t)row * N + col] = f2bf(v);
                else
                    Cf[(size_t)row * N + col] = v + resid[(size_t)row * N + col];
            }
        }
    }
}

// ---------------- V transpose: per-window V[kk][e] -> Vt[win][e][kk] ----------------
__global__ void transpose_v(const u16* __restrict__ qkv, u16* __restrict__ vt) {
    __shared__ u16 lt[64][72];  // padded
    const int bx = blockIdx.x;
    const int kt = bx & 3, et = (bx >> 2) & 15, win = bx >> 6;
    const int t = threadIdx.x;
#pragma unroll
    for (int p = 0; p < 2; ++p) {
        int e = p * 2048 + t * 8;
        int kr = e >> 6, c = e & 63;
        short8 v = *(const short8*)(qkv + (size_t)(win * 256 + kt * 64 + kr) * 3072 + 2048 + et * 64 + c);
#pragma unroll
        for (int j = 0; j < 8; ++j) lt[c + j][kr] = (u16)v[j];
    }
    __syncthreads();
#pragma unroll
    for (int p = 0; p < 2; ++p) {
        int e = p * 2048 + t * 8;
        int er = e >> 6, kc = e & 63;
        short8 v = *(const short8*)(&lt[er][kc]);
        *(short8*)(vt + (size_t)(win * 1024 + et * 64 + er) * 256 + kt * 64 + kc) = v;
    }
}

// ---------------- windowed causal attention ----------------
// One block = (window win, 64 q-rows qc). 4 waves. QK^T (full E=1024) -> softmax -> PV.
__global__ __launch_bounds__(256, 1) void attn_win(
    const u16* __restrict__ qkv, const u16* __restrict__ vt, u16* __restrict__ attn)
{
    // LDS: [0,65792) S fp32 [64][257] (phase2) / Qt(8K)+Kt(32K) (phase1) / Vl(32K) (phase3)
    //      [65792, 98560) P bf16 [64][256] swizzled
    //      [98560, 99584) rmax, [99584, 100608) rsum
    __shared__ __align__(16) char smem[100608];
    float* S = (float*)smem;
    u16* P = (u16*)(smem + 65792);
    float* rmax = (float*)(smem + 98560);
    float* rsum = (float*)(smem + 99584);
    u16* Qt = (u16*)smem;
    u16* Kt = (u16*)(smem + 8192);
    u16* Vl = (u16*)smem;

    const int t = threadIdx.x;
    const int lane = t & 63, wv = t >> 6;
    const int l15 = lane & 15, lk = lane >> 4;
    const int bx = blockIdx.x;
    const int win = bx >> 2, qc = bx & 3;
    const size_t qrow0 = (size_t)win * 256 + qc * 64;
    const size_t krow0 = (size_t)win * 256;

    f32x4 acc[4][4];
#pragma unroll
    for (int m = 0; m < 4; ++m)
#pragma unroll
        for (int n = 0; n < 4; ++n)
            acc[m][n] = (f32x4){0.f, 0.f, 0.f, 0.f};

    // ---- phase 1: scores = Q @ K^T over E=1024 ----
    for (int e0 = 0; e0 < 1024; e0 += 64) {
        __syncthreads();
#pragma unroll
        for (int p = 0; p < 2; ++p) {  // Q tile 64x64
            int e = p * 2048 + t * 8;
            int row = e >> 6, col = e & 63;
            short8 v = *(const short8*)(qkv + (qrow0 + row) * 3072 + e0 + col);
            *(short8*)((char*)Qt + row * 128 + ((col * 2) ^ ((row & 7) << 4))) = v;
        }
#pragma unroll
        for (int p = 0; p < 8; ++p) {  // K tile 256x64
            int e = p * 2048 + t * 8;
            int row = e >> 6, col = e & 63;
            short8 v = *(const short8*)(qkv + (krow0 + row) * 3072 + 1024 + e0 + col);
            *(short8*)((char*)Kt + row * 128 + ((col * 2) ^ ((row & 7) << 4))) = v;
        }
        __syncthreads();
#pragma unroll
        for (int ks = 0; ks < 2; ++ks) {
            const int bc = ks * 64 + lk * 16;
            short8 af[4], bfr[4];
#pragma unroll
            for (int m = 0; m < 4; ++m) {
                int row = m * 16 + l15;
                af[m] = *(const short8*)((char*)Qt + row * 128 + (bc ^ ((row & 7) << 4)));
            }
#pragma unroll
            for (int n = 0; n < 4; ++n) {
                int row = wv * 64 + n * 16 + l15;
                bfr[n] = *(const short8*)((char*)Kt + row * 128 + (bc ^ ((row & 7) << 4)));
            }
#pragma unroll
            for (int m = 0; m < 4; ++m)
#pragma unroll
                for (int n = 0; n < 4; ++n)
                    acc[m][n] = __builtin_amdgcn_mfma_f32_16x16x32_bf16(af[m], bfr[n], acc[m][n], 0, 0, 0);
        }
    }
    __syncthreads();  // protect Qt/Kt region before S overwrite

    // ---- phase 2: mask + scale -> S, softmax -> P (bf16, folded 1/sum) ----
#pragma unroll
    for (int m = 0; m < 4; ++m) {
#pragma unroll
        for (int n = 0; n < 4; ++n) {
            int col = wv * 64 + n * 16 + l15;
#pragma unroll
            for (int r = 0; r < 4; ++r) {
                int row = m * 16 + lk * 4 + r;
                int qpos = qc * 64 + row;
                float v = acc[m][n][r] * 0.125f;
                S[row * 257 + col] = (col <= qpos) ? v : -1e30f;
            }
        }
    }
    __syncthreads();
    {
        const int row = t & 63, q4 = t >> 6;
        float* Sr = S + row * 257 + q4 * 64;
        float lmax = -1e30f;
        for (int i = 0; i < 64; ++i) lmax = fmaxf(lmax, Sr[i]);
        rmax[row * 4 + q4] = lmax;
        __syncthreads();
        float m4 = fmaxf(fmaxf(rmax[row * 4], rmax[row * 4 + 1]),
                         fmaxf(rmax[row * 4 + 2], rmax[row * 4 + 3]));
        float lsum = 0.f;
        for (int i = 0; i < 64; ++i) {
            float e = __expf(Sr[i] - m4);
            Sr[i] = e;
            lsum += e;
        }
        rsum[row * 4 + q4] = lsum;
        __syncthreads();
        float inv = 1.f / (rsum[row * 4] + rsum[row * 4 + 1] + rsum[row * 4 + 2] + rsum[row * 4 + 3]);
#pragma unroll
        for (int i8 = 0; i8 < 8; ++i8) {
            short8 pv;
#pragma unroll
            for (int j = 0; j < 8; ++j) pv[j] = (short)f2bf(Sr[i8 * 8 + j] * inv);
            int col = q4 * 64 + i8 * 8;
            *(short8*)((char*)P + row * 512 + ((col * 2) ^ ((row & 7) << 4))) = pv;
        }
    }

    // ---- phase 3: out = P @ V via pre-transposed Vt ----
    for (int n0 = 0; n0 < 1024; n0 += 64) {
        __syncthreads();
#pragma unroll
        for (int p = 0; p < 8; ++p) {  // Vt chunk [64 e][256 kk]
            int e = p * 2048 + t * 8;
            int row = e >> 8, col = e & 255;
            short8 v = *(const short8*)(vt + ((size_t)win * 1024 + n0 + row) * 256 + col);
            *(short8*)((char*)Vl + row * 512 + ((col * 2) ^ ((row & 7) << 4))) = v;
        }
        __syncthreads();
        f32x4 acc2[4];
#pragma unroll
        for (int m = 0; m < 4; ++m) acc2[m] = (f32x4){0.f, 0.f, 0.f, 0.f};
#pragma unroll
        for (int ks = 0; ks < 8; ++ks) {
            const int bc = ks * 64 + lk * 16;
            short8 af[4];
#pragma unroll
            for (int m = 0; m < 4; ++m) {
                int row = m * 16 + l15;
                af[m] = *(const short8*)((char*)P + row * 512 + (bc ^ ((row & 7) << 4)));
            }
            int vrow = wv * 16 + l15;
            short8 bfr = *(const short8*)((char*)Vl + vrow * 512 + (bc ^ ((vrow & 7) << 4)));
#pragma unroll
            for (int m = 0; m < 4; ++m)
                acc2[m] = __builtin_amdgcn_mfma_f32_16x16x32_bf16(af[m], bfr, acc2[m], 0, 0, 0);
        }
#pragma unroll
        for (int m = 0; m < 4; ++m) {
#pragma unroll
            for (int r = 0; r < 4; ++r) {
                int row = m * 16 + lk * 4 + r;
                int col = n0 + wv * 16 + l15;
                attn[(qrow0 + row) * 1024 + col] = f2bf(acc2[m][r]);
            }
        }
    }
}

extern "C" void kernel_launch(void* const* d_in, const int* in_sizes, int n_in,
                              void* d_out, int out_size, void* d_ws, size_t ws_size,
                              hipStream_t stream) {
    const float* x  = (const float*)d_in[0];
    const float* Wq = (const float*)d_in[1];
    const float* bq = (const float*)d_in[2];
    const float* Wk = (const float*)d_in[3];
    const float* bk = (const float*)d_in[4];
    const float* Wv = (const float*)d_in[5];
    const float* bv = (const float*)d_in[6];
    const float* Wo = (const float*)d_in[7];
    const float* bo = (const float*)d_in[8];
    float* out = (float*)d_out;

    char* ws = (char*)d_ws;
    u16* xb    = (u16*)(ws);                  // 16384x1024 bf16   (33.55 MB)
    u16* wqkv  = (u16*)(ws + 33554432);       // 3072x1024 bf16    (6.29 MB)
    u16* wo_b  = (u16*)(ws + 39845888);       // 1024x1024 bf16    (2.10 MB)
    u16* qkvb  = (u16*)(ws + 41943040);       // 16384x3072 bf16   (100.66 MB)
    u16* vtb   = (u16*)(ws + 142606336);      // 64x1024x256 bf16  (33.55 MB)
    u16* attnb = (u16*)(ws + 176160768);      // 16384x1024 bf16   (33.55 MB)
    // total 209715200 bytes

    cast_f32_bf16<<<8192, 256, 0, stream>>>(x, xb, 16777216);
    cast_f32_bf16<<<512, 256, 0, stream>>>(Wq, wqkv, 1048576);
    cast_f32_bf16<<<512, 256, 0, stream>>>(Wk, wqkv + 1048576, 1048576);
    cast_f32_bf16<<<512, 256, 0, stream>>>(Wv, wqkv + 2097152, 1048576);
    cast_f32_bf16<<<512, 256, 0, stream>>>(Wo, wo_b, 1048576);

    gemm_bt<0><<<dim3(24, 128), 256, 0, stream>>>(xb, wqkv, 16384, 3072, 1024,
                                                  bq, bk, bv, qkvb, nullptr, nullptr);
    transpose_v<<<4096, 256, 0, stream>>>(qkvb, vtb);
    attn_win<<<256, 256, 0, stream>>>(qkvb, vtb, attnb);
    gemm_bt<1><<<dim3(8, 128), 256, 0, stream>>>(attnb, wo_b, 16384, 1024, 1024,
                                                 bo, nullptr, nullptr, nullptr, out, x);
}

// Round 2
// 275.037 us; speedup vs baseline: 1.0208x; 1.0208x over previous
//
#include <hip/hip_runtime.h>
#include <hip/hip_bf16.h>

// LocalSelfAttention: B=4, S=4096, E=1024, WINDOW=256, SCALE=0.125
// Pipeline: cast -> QKV gemm (256^2 tile, 3-buf ring, global_load_lds, counted vmcnt)
//           -> V transpose -> windowed attn -> O gemm (+bias+residual)

typedef unsigned short u16;
typedef __attribute__((ext_vector_type(8))) short short8;   // 8 bf16 (4 VGPRs)
typedef __attribute__((ext_vector_type(4))) float f32x4;

__device__ __forceinline__ u16 f2bf(float f) {
    __hip_bfloat16 h = __float2bfloat16(f);
    return __builtin_bit_cast(u16, h);
}

__device__ __forceinline__ void gl_lds16(const u16* g, u16* l) {
    __builtin_amdgcn_global_load_lds(
        (const __attribute__((address_space(1))) void*)g,
        (__attribute__((address_space(3))) void*)l,
        16, 0, 0);
}

// ---------------- cast fp32 -> bf16, vectorized ----------------
__global__ void cast_f32_bf16(const float* __restrict__ src, u16* __restrict__ dst, int n) {
    int i = (blockIdx.x * 256 + threadIdx.x) * 8;
    if (i >= n) return;
    const float4* s = (const float4*)(src + i);
    float4 a = s[0], b = s[1];
    short8 o;
    o[0] = (short)f2bf(a.x); o[1] = (short)f2bf(a.y); o[2] = (short)f2bf(a.z); o[3] = (short)f2bf(a.w);
    o[4] = (short)f2bf(b.x); o[5] = (short)f2bf(b.y); o[6] = (short)f2bf(b.z); o[7] = (short)f2bf(b.w);
    *(short8*)(dst + i) = o;
}

// ---------------- GEMM 256x256 tile, BK=32, 8 waves, 3-buffer LDS ring ----------------
// C[M,N] = A[M,K] @ B[N,K]^T + bias.  A,B bf16 K-major.
// EPI=0: bf16 out, bias selected from 3 arrays by col/1024 (QKV fused).
// EPI=1: fp32 out = acc + bias0 + resid (O-projection + residual).
//
// LDS layout per buffer: A-tile 256x32 bf16 packed as [128 rows][8 slots of 16B],
// physical slot = logical slot ^ (row&7).  logical slot s: m = 2*row + (s>>2),
// k-chunk = (s&3)*8.  global_load_lds writes linearly; the per-lane GLOBAL source
// address is pre-swizzled so reads can apply the same XOR (m173/m201 pattern).
//
// Schedule (race-free, 1 barrier/iter): per iter t:
//   vmcnt(4)  -- own tile-t loads landed (tile t+1's 4 loads stay in flight)
//   s_barrier -- all waves' tile-t loads landed; buf[(t-1)%3] free
//   issue tile t+2 -> buf[(t+2)%3] == buf[(t-1)%3]
//   ds_read frags + 32 MFMA (setprio-wrapped)
template <int EPI>
__global__ __launch_bounds__(512, 2) void gemm256(
    const u16* __restrict__ A, const u16* __restrict__ B,
    int M, int N, int K,
    const float* __restrict__ bias0, const float* __restrict__ bias1, const float* __restrict__ bias2,
    u16* __restrict__ Cb, float* __restrict__ Cf, const float* __restrict__ resid)
{
    __shared__ __align__(16) u16 sm[3 * 16384];   // 3 x (A 16KB + B 16KB) = 96 KiB
    const int t = threadIdx.x;
    const int lane = t & 63, w = t >> 6;
    const int l15 = lane & 15, lk = lane >> 4;
    const int wm = w >> 2, wn = w & 3;
    const int m0 = blockIdx.y * 256, n0 = blockIdx.x * 256;

    // staging geometry (constant per thread)
    const int sr_base = w * 16 + (lane >> 3);  // LDS 128B-row index, + c*8
    const int sp = lane & 7;                   // physical 16B slot

    f32x4 acc[8][4];
#pragma unroll
    for (int mf = 0; mf < 8; ++mf)
#pragma unroll
        for (int nf = 0; nf < 4; ++nf)
            acc[mf][nf] = (f32x4){0.f, 0.f, 0.f, 0.f};

    const int NT = K >> 5;   // K / 32

    auto STAGE = [&](int tt, int bi) {
        u16* bufA = sm + bi * 16384;
        u16* bufB = bufA + 8192;
        const int k0 = tt << 5;
#pragma unroll
        for (int c = 0; c < 2; ++c) {
            int r = sr_base + c * 8;
            int s = sp ^ (r & 7);            // logical slot this lane must fetch
            int m = 2 * r + (s >> 2);
            int koff = k0 + (s & 3) * 8;
            gl_lds16(A + (size_t)(m0 + m) * K + koff, bufA + w * 1024 + c * 512);
            gl_lds16(B + (size_t)(n0 + m) * K + koff, bufB + w * 1024 + c * 512);
        }
    };

    STAGE(0, 0);
    STAGE(1, 1);

    int bi = 0;
    for (int tt = 0; tt < NT; ++tt) {
        if (tt == NT - 1) asm volatile("s_waitcnt vmcnt(0)" ::: "memory");
        else              asm volatile("s_waitcnt vmcnt(4)" ::: "memory");
        __builtin_amdgcn_s_barrier();
        asm volatile("" ::: "memory");

        if (tt + 2 < NT) {
            int b2 = bi + 2; if (b2 >= 3) b2 -= 3;
            STAGE(tt + 2, b2);
        }

        const u16* bufA = sm + bi * 16384;
        const u16* bufB = bufA + 8192;

        short8 bfr[4];
#pragma unroll
        for (int nf = 0; nf < 4; ++nf) {
            int n = wn * 64 + nf * 16 + l15;
            int r = n >> 1;
            int s = ((n & 1) << 2) | lk;
            bfr[nf] = *(const short8*)(bufB + r * 64 + ((s ^ (r & 7)) << 3));
        }
        __builtin_amdgcn_s_setprio(1);
#pragma unroll
        for (int mf = 0; mf < 8; ++mf) {
            int m = wm * 128 + mf * 16 + l15;
            int r = m >> 1;
            int s = ((m & 1) << 2) | lk;
            short8 af = *(const short8*)(bufA + r * 64 + ((s ^ (r & 7)) << 3));
#pragma unroll
            for (int nf = 0; nf < 4; ++nf)
                acc[mf][nf] = __builtin_amdgcn_mfma_f32_16x16x32_bf16(af, bfr[nf], acc[mf][nf], 0, 0, 0);
        }
        __builtin_amdgcn_s_setprio(0);

        ++bi; if (bi >= 3) bi = 0;
    }

    // epilogue
#pragma unroll
    for (int mf = 0; mf < 8; ++mf) {
#pragma unroll
        for (int nf = 0; nf < 4; ++nf) {
            int col = n0 + wn * 64 + nf * 16 + l15;
            float bv;
            if (EPI == 0)
                bv = (col < 1024) ? bias0[col] : (col < 2048) ? bias1[col - 1024] : bias2[col - 2048];
            else
                bv = bias0[col];
#pragma unroll
            for (int r = 0; r < 4; ++r) {
                int row = m0 + wm * 128 + mf * 16 + lk * 4 + r;
                float v = acc[mf][nf][r] + bv;
                if (EPI == 0)
                    Cb[(size_t)row * N + col] = f2bf(v);
                else
                    Cf[(size_t)row * N + col] = v + resid[(size_t)row * N + col];
            }
        }
    }
}

// ---------------- V transpose: per-window V[kk][e] -> Vt[win][e][kk] ----------------
__global__ void transpose_v(const u16* __restrict__ qkv, u16* __restrict__ vt) {
    __shared__ u16 lt[64][72];  // padded
    const int bx = blockIdx.x;
    const int kt = bx & 3, et = (bx >> 2) & 15, win = bx >> 6;
    const int t = threadIdx.x;
#pragma unroll
    for (int p = 0; p < 2; ++p) {
        int e = p * 2048 + t * 8;
        int kr = e >> 6, c = e & 63;
        short8 v = *(const short8*)(qkv + (size_t)(win * 256 + kt * 64 + kr) * 3072 + 2048 + et * 64 + c);
#pragma unroll
        for (int j = 0; j < 8; ++j) lt[c + j][kr] = (u16)v[j];
    }
    __syncthreads();
#pragma unroll
    for (int p = 0; p < 2; ++p) {
        int e = p * 2048 + t * 8;
        int er = e >> 6, kc = e & 63;
        short8 v = *(const short8*)(&lt[er][kc]);
        *(short8*)(vt + (size_t)(win * 1024 + et * 64 + er) * 256 + kt * 64 + kc) = v;
    }
}

// ---------------- windowed causal attention ----------------
// One block = (window win, 64 q-rows qc). 4 waves. QK^T (full E=1024) -> softmax -> PV.
__global__ __launch_bounds__(256, 1) void attn_win(
    const u16* __restrict__ qkv, const u16* __restrict__ vt, u16* __restrict__ attn)
{
    __shared__ __align__(16) char smem[100608];
    float* S = (float*)smem;
    u16* P = (u16*)(smem + 65792);
    float* rmax = (float*)(smem + 98560);
    float* rsum = (float*)(smem + 99584);
    u16* Qt = (u16*)smem;
    u16* Kt = (u16*)(smem + 8192);
    u16* Vl = (u16*)smem;

    const int t = threadIdx.x;
    const int lane = t & 63, wv = t >> 6;
    const int l15 = lane & 15, lk = lane >> 4;
    const int bx = blockIdx.x;
    const int win = bx >> 2, qc = bx & 3;
    const size_t qrow0 = (size_t)win * 256 + qc * 64;
    const size_t krow0 = (size_t)win * 256;

    f32x4 acc[4][4];
#pragma unroll
    for (int m = 0; m < 4; ++m)
#pragma unroll
        for (int n = 0; n < 4; ++n)
            acc[m][n] = (f32x4){0.f, 0.f, 0.f, 0.f};

    // ---- phase 1: scores = Q @ K^T over E=1024 ----
    for (int e0 = 0; e0 < 1024; e0 += 64) {
        __syncthreads();
#pragma unroll
        for (int p = 0; p < 2; ++p) {  // Q tile 64x64
            int e = p * 2048 + t * 8;
            int row = e >> 6, col = e & 63;
            short8 v = *(const short8*)(qkv + (qrow0 + row) * 3072 + e0 + col);
            *(short8*)((char*)Qt + row * 128 + ((col * 2) ^ ((row & 7) << 4))) = v;
        }
#pragma unroll
        for (int p = 0; p < 8; ++p) {  // K tile 256x64
            int e = p * 2048 + t * 8;
            int row = e >> 6, col = e & 63;
            short8 v = *(const short8*)(qkv + (krow0 + row) * 3072 + 1024 + e0 + col);
            *(short8*)((char*)Kt + row * 128 + ((col * 2) ^ ((row & 7) << 4))) = v;
        }
        __syncthreads();
#pragma unroll
        for (int ks = 0; ks < 2; ++ks) {
            const int bc = ks * 64 + lk * 16;
            short8 af[4], bfr[4];
#pragma unroll
            for (int m = 0; m < 4; ++m) {
                int row = m * 16 + l15;
                af[m] = *(const short8*)((char*)Qt + row * 128 + (bc ^ ((row & 7) << 4)));
            }
#pragma unroll
            for (int n = 0; n < 4; ++n) {
                int row = wv * 64 + n * 16 + l15;
                bfr[n] = *(const short8*)((char*)Kt + row * 128 + (bc ^ ((row & 7) << 4)));
            }
#pragma unroll
            for (int m = 0; m < 4; ++m)
#pragma unroll
                for (int n = 0; n < 4; ++n)
                    acc[m][n] = __builtin_amdgcn_mfma_f32_16x16x32_bf16(af[m], bfr[n], acc[m][n], 0, 0, 0);
        }
    }
    __syncthreads();

    // ---- phase 2: mask + scale -> S, softmax -> P ----
#pragma unroll
    for (int m = 0; m < 4; ++m) {
#pragma unroll
        for (int n = 0; n < 4; ++n) {
            int col = wv * 64 + n * 16 + l15;
#pragma unroll
            for (int r = 0; r < 4; ++r) {
                int row = m * 16 + lk * 4 + r;
                int qpos = qc * 64 + row;
                float v = acc[m][n][r] * 0.125f;
                S[row * 257 + col] = (col <= qpos) ? v : -1e30f;
            }
        }
    }
    __syncthreads();
    {
        const int row = t & 63, q4 = t >> 6;
        float* Sr = S + row * 257 + q4 * 64;
        float lmax = -1e30f;
        for (int i = 0; i < 64; ++i) lmax = fmaxf(lmax, Sr[i]);
        rmax[row * 4 + q4] = lmax;
        __syncthreads();
        float m4 = fmaxf(fmaxf(rmax[row * 4], rmax[row * 4 + 1]),
                         fmaxf(rmax[row * 4 + 2], rmax[row * 4 + 3]));
        float lsum = 0.f;
        for (int i = 0; i < 64; ++i) {
            float e = __expf(Sr[i] - m4);
            Sr[i] = e;
            lsum += e;
        }
        rsum[row * 4 + q4] = lsum;
        __syncthreads();
        float inv = 1.f / (rsum[row * 4] + rsum[row * 4 + 1] + rsum[row * 4 + 2] + rsum[row * 4 + 3]);
#pragma unroll
        for (int i8 = 0; i8 < 8; ++i8) {
            short8 pv;
#pragma unroll
            for (int j = 0; j < 8; ++j) pv[j] = (short)f2bf(Sr[i8 * 8 + j] * inv);
            int col = q4 * 64 + i8 * 8;
            *(short8*)((char*)P + row * 512 + ((col * 2) ^ ((row & 7) << 4))) = pv;
        }
    }

    // ---- phase 3: out = P @ V via pre-transposed Vt ----
    for (int n0 = 0; n0 < 1024; n0 += 64) {
        __syncthreads();
#pragma unroll
        for (int p = 0; p < 8; ++p) {
            int e = p * 2048 + t * 8;
            int row = e >> 8, col = e & 255;
            short8 v = *(const short8*)(vt + ((size_t)win * 1024 + n0 + row) * 256 + col);
            *(short8*)((char*)Vl + row * 512 + ((col * 2) ^ ((row & 7) << 4))) = v;
        }
        __syncthreads();
        f32x4 acc2[4];
#pragma unroll
        for (int m = 0; m < 4; ++m) acc2[m] = (f32x4){0.f, 0.f, 0.f, 0.f};
#pragma unroll
        for (int ks = 0; ks < 8; ++ks) {
            const int bc = ks * 64 + lk * 16;
            short8 af[4];
#pragma unroll
            for (int m = 0; m < 4; ++m) {
                int row = m * 16 + l15;
                af[m] = *(const short8*)((char*)P + row * 512 + (bc ^ ((row & 7) << 4)));
            }
            int vrow = wv * 16 + l15;
            short8 bfr = *(const short8*)((char*)Vl + vrow * 512 + (bc ^ ((vrow & 7) << 4)));
#pragma unroll
            for (int m = 0; m < 4; ++m)
                acc2[m] = __builtin_amdgcn_mfma_f32_16x16x32_bf16(af[m], bfr, acc2[m], 0, 0, 0);
        }
#pragma unroll
        for (int m = 0; m < 4; ++m) {
#pragma unroll
            for (int r = 0; r < 4; ++r) {
                int row = m * 16 + lk * 4 + r;
                int col = n0 + wv * 16 + l15;
                attn[(qrow0 + row) * 1024 + col] = f2bf(acc2[m][r]);
            }
        }
    }
}

extern "C" void kernel_launch(void* const* d_in, const int* in_sizes, int n_in,
                              void* d_out, int out_size, void* d_ws, size_t ws_size,
                              hipStream_t stream) {
    const float* x  = (const float*)d_in[0];
    const float* Wq = (const float*)d_in[1];
    const float* bq = (const float*)d_in[2];
    const float* Wk = (const float*)d_in[3];
    const float* bk = (const float*)d_in[4];
    const float* Wv = (const float*)d_in[5];
    const float* bv = (const float*)d_in[6];
    const float* Wo = (const float*)d_in[7];
    const float* bo = (const float*)d_in[8];
    float* out = (float*)d_out;

    char* ws = (char*)d_ws;
    u16* xb    = (u16*)(ws);                  // 16384x1024 bf16
    u16* wqkv  = (u16*)(ws + 33554432);       // 3072x1024 bf16
    u16* wo_b  = (u16*)(ws + 39845888);       // 1024x1024 bf16
    u16* qkvb  = (u16*)(ws + 41943040);       // 16384x3072 bf16
    u16* vtb   = (u16*)(ws + 142606336);      // 64x1024x256 bf16
    u16* attnb = (u16*)(ws + 176160768);      // 16384x1024 bf16

    cast_f32_bf16<<<8192, 256, 0, stream>>>(x, xb, 16777216);
    cast_f32_bf16<<<512, 256, 0, stream>>>(Wq, wqkv, 1048576);
    cast_f32_bf16<<<512, 256, 0, stream>>>(Wk, wqkv + 1048576, 1048576);
    cast_f32_bf16<<<512, 256, 0, stream>>>(Wv, wqkv + 2097152, 1048576);
    cast_f32_bf16<<<512, 256, 0, stream>>>(Wo, wo_b, 1048576);

    gemm256<0><<<dim3(12, 64), 512, 0, stream>>>(xb, wqkv, 16384, 3072, 1024,
                                                 bq, bk, bv, qkvb, nullptr, nullptr);
    transpose_v<<<4096, 256, 0, stream>>>(qkvb, vtb);
    attn_win<<<256, 256, 0, stream>>>(qkvb, vtb, attnb);
    gemm256<1><<<dim3(4, 64), 512, 0, stream>>>(attnb, wo_b, 16384, 1024, 1024,
                                                bo, nullptr, nullptr, nullptr, out, x);
}